// Round 7
// baseline (150.139 us; speedup 1.0000x reference)
//
#include <hip/hip_runtime.h>
#include <math.h>

// ---- all scratch as device globals (allocated at module load; no d_ws dependency) ----
__device__ float  g_norms[16];
__device__ float  g_partial[1024];
__device__ float2 g_cs[65536];         // (cos phs, sin phs) per pixel
__device__ float  g_I[65536];          // I_est scratch copy
__device__ float2 g_tw[512];           // tw[h+k] = exp(-i*pi*k/h), h=1,2,4,...,256
__device__ float2 g_SfA[256*512];      // 1 MB
__device__ float2 g_Sf [512*512];      // 2 MB (stored in mixed-radix pi order)
__device__ float2 g_F  [16*256*256];   // 8 MB
__device__ float2 g_KA [16*256*512];   // 16 MB
__device__ float2 g_P  [16*256*512];   // 16 MB

__device__ __forceinline__ int rev8(int x){ return (int)(__brev((unsigned)x) >> 24); }
__device__ __forceinline__ int rev9(int x){ return (int)(__brev((unsigned)x) >> 23); }
// base-4 digit reversal of an 8-bit index (involution)
__device__ __forceinline__ int rev4d8(int x){
  return ((x&3)<<6) | (((x>>2)&3)<<4) | (((x>>4)&3)<<2) | ((x>>6)&3);
}

__device__ __forceinline__ float2 cadd(float2 a, float2 b){ return make_float2(a.x+b.x, a.y+b.y); }
__device__ __forceinline__ float2 csub(float2 a, float2 b){ return make_float2(a.x-b.x, a.y-b.y); }
__device__ __forceinline__ float2 cmul(float2 a, float2 b){ return make_float2(a.x*b.x - a.y*b.y, a.x*b.y + a.y*b.x); }
__device__ __forceinline__ float2 cmulj(float2 a, float2 b){ return make_float2(a.x*b.x + a.y*b.y, a.y*b.x - a.x*b.y); } // a*conj(b)
__device__ __forceinline__ float2 addi(float2 a, float2 b){ return make_float2(a.x - b.y, a.y + b.x); } // a + i*b
__device__ __forceinline__ float2 subi(float2 a, float2 b){ return make_float2(a.x + b.y, a.y - b.x); } // a - i*b

#define OUT_W(idx, val) do{ int _i = (idx); if ((unsigned)_i < (unsigned)osz) out[_i] = (val); }while(0)

// ---- twiddle table init (once per call; ~1us) ----
__global__ void k_twiddle(){
  int i = blockIdx.x*256 + threadIdx.x;
  if (i >= 512) return;
  if (i == 0){ g_tw[0] = make_float2(1.f, 0.f); return; }
  int h = 1 << (31 - __clz(i));
  int k = i - h;
  double a = -M_PI * (double)k / (double)h;
  g_tw[i] = make_float2((float)cos(a), (float)sin(a));
}

// ---- single-column radix-2 FFTs, separate re/im (row kernels) ----
template<int N, bool INV>
__device__ inline void fft_dif_sc(float* re, float* im, int tid, int nthr){
  for (int half = N >> 1; half >= 1; half >>= 1){
    __syncthreads();
    for (int b = tid; b < (N>>1); b += nthr){
      int k  = b & (half - 1);
      int i0 = ((b - k) << 1) + k;
      int i1 = i0 + half;
      float2 w = g_tw[half + k];
      float wy = INV ? -w.y : w.y;
      float ar = re[i0], ai = im[i0], br = re[i1], bi = im[i1];
      float dr = ar - br, di = ai - bi;
      re[i0] = ar + br; im[i0] = ai + bi;
      re[i1] = dr*w.x - di*wy;
      im[i1] = dr*wy + di*w.x;
    }
  }
  __syncthreads();
}

// ==== radix-4 multi-column machinery (8 cols/block, LDS float2 [row*9 + col]) ====

// fold: first radix-4 DIF stage (q=128) for 512-pt with input rows 256..511 == 0.
__device__ __forceinline__ void fold512_load(const float2* src, float2* buf, int c, int rr){
  for (int i = rr; i < 128; i += 32){
    float2 a = src[(size_t)i*512];
    float2 b = src[(size_t)(i+128)*512];
    float2 w1 = g_tw[256+i], w2 = g_tw[128+i];
    float2 w3 = cmul(w1, w2);
    buf[i*9+c]       = cadd(a,b);
    buf[(i+128)*9+c] = cmul(subi(a,b), w1);
    buf[(i+256)*9+c] = cmul(csub(a,b), w2);
    buf[(i+384)*9+c] = cmul(addi(a,b), w3);
  }
}

// forward radix-4 stages q = 32, 8, 2 (after the folded q=128 stage)
__device__ __forceinline__ void dif4_stages_512(float2* buf, int c, int rr){
  #pragma unroll
  for (int q = 32; q >= 2; q >>= 2){
    __syncthreads();
    for (int g = rr; g < 128; g += 32){
      int k = g & (q-1);
      int base = ((g - k) << 2) + k;
      float2 x0 = buf[base*9+c], x1 = buf[(base+q)*9+c];
      float2 x2 = buf[(base+2*q)*9+c], x3 = buf[(base+3*q)*9+c];
      float2 t0=cadd(x0,x2), t1=csub(x0,x2), t2=cadd(x1,x3), t3=csub(x1,x3);
      float2 y0=cadd(t0,t2), y1=subi(t1,t3), y2=csub(t0,t2), y3=addi(t1,t3);
      float2 w1 = g_tw[2*q+k], w2 = g_tw[q+k];
      float2 w3 = cmul(w1,w2);
      buf[base*9+c]       = y0;
      buf[(base+q)*9+c]   = cmul(y1,w1);
      buf[(base+2*q)*9+c] = cmul(y2,w2);
      buf[(base+3*q)*9+c] = cmul(y3,w3);
    }
  }
}

// ---------------- g-MLP: weights read uniformly from global (scalar loads, no LDS) ----------------
__global__ __launch_bounds__(256) void k_gmlp(
    const float* __restrict__ gw0, const float* __restrict__ gb0,
    const float* __restrict__ gw1, const float* __restrict__ gb1,
    const float* __restrict__ l1w, const float* __restrict__ l1b,
    const float* __restrict__ gw2, const float* __restrict__ gb2,
    const float* __restrict__ l2w, const float* __restrict__ l2b,
    const float* __restrict__ gw3, const float* __restrict__ gb3,
    float* out, int osz, int offG, int offPhs, int interleaved)
{
  int tid = threadIdx.x;
  int p = blockIdx.x * 256 + tid;
  int r = p >> 8, c = p & 255;
  float x = (float)(-1.0 + (2.0 * c) / 255.0);
  float y = (float)(-1.0 + (2.0 * r) / 255.0);

  float h0[32];
  #pragma unroll
  for (int j = 0; j < 32; j++) h0[j] = gb0[j];

  // sin/cos(i*x) via recurrence from sincos(x)
  float sx1, cx1, sy1, cy1;
  sincosf(x, &sx1, &cx1);
  sincosf(y, &sy1, &cy1);
  float sx = sx1, cx = cx1, sy = sy1, cy = cy1;
  for (int i = 1; i <= 15; i++){
    const float* r0 = gw0 + (4*(i-1)+0)*32;
    const float* r1 = gw0 + (4*(i-1)+1)*32;
    const float* r2 = gw0 + (4*(i-1)+2)*32;
    const float* r3 = gw0 + (4*(i-1)+3)*32;
    #pragma unroll
    for (int j = 0; j < 32; j++)
      h0[j] += sx*r0[j] + sy*r1[j] + cx*r2[j] + cy*r3[j];
    float nsx = sx*cx1 + cx*sx1, ncx = cx*cx1 - sx*sx1;
    float nsy = sy*cy1 + cy*sy1, ncy = cy*cy1 - sy*sy1;
    sx = nsx; cx = ncx; sy = nsy; cy = ncy;
  }

  float h1[32];
  #pragma unroll
  for (int j = 0; j < 32; j++) h1[j] = gb1[j];
  for (int k = 0; k < 32; k++){
    float v = h0[k];
    const float* row = gw1 + k*32;
    #pragma unroll
    for (int j = 0; j < 32; j++) h1[j] += v * row[j];
  }
  {
    float m = 0.f;
    #pragma unroll
    for (int j = 0; j < 32; j++) m += h1[j];
    m *= (1.0f/32.0f);
    float vv = 0.f;
    #pragma unroll
    for (int j = 0; j < 32; j++){ float d = h1[j]-m; vv += d*d; }
    vv *= (1.0f/32.0f);
    float inv = rsqrtf(vv + 1e-5f);
    #pragma unroll
    for (int j = 0; j < 32; j++){
      float t = (h1[j]-m)*inv*l1w[j] + l1b[j];
      h1[j] = (t > 0.f) ? t : 0.01f*t;
    }
  }

  float h2[32];
  #pragma unroll
  for (int j = 0; j < 32; j++) h2[j] = gb2[j];
  for (int k = 0; k < 32; k++){
    float v = h1[k];
    const float* row = gw2 + k*32;
    #pragma unroll
    for (int j = 0; j < 32; j++) h2[j] += v * row[j];
  }
  {
    float m = 0.f;
    #pragma unroll
    for (int j = 0; j < 32; j++) m += h2[j];
    m *= (1.0f/32.0f);
    float vv = 0.f;
    #pragma unroll
    for (int j = 0; j < 32; j++){ float d = h2[j]-m; vv += d*d; }
    vv *= (1.0f/32.0f);
    float inv = rsqrtf(vv + 1e-5f);
    #pragma unroll
    for (int j = 0; j < 32; j++){
      float t = (h2[j]-m)*inv*l2w[j] + l2b[j];
      h2[j] = (t > 0.f) ? t : 0.01f*t;
    }
  }

  float phs = gb3[0];
  #pragma unroll
  for (int k = 0; k < 32; k++) phs += h2[k]*gw3[k];

  float sp, cp; sincosf(phs, &sp, &cp);
  g_cs[p] = make_float2(cp, sp);

  #pragma unroll
  for (int b = 0; b < 16; b++){
    OUT_W(offPhs + b*65536 + p, phs);
    if (interleaved){
      int gi = offG + 2*(b*65536 + p);
      if (gi + 1 < osz) *(float2*)(out + gi) = make_float2(cp, sp);
    } else {
      OUT_W(offG + b*65536 + p, cp);
    }
  }
}

// ---------------- patch MLPs -> I_est (scalar weight loads, float4 data loads) ----------------
__global__ __launch_bounds__(256) void k_patch(
    const float* __restrict__ pdata, const float* __restrict__ rw0, const float* __restrict__ rb0,
    const float* __restrict__ rw1, const float* __restrict__ rb1,
    const float* __restrict__ rw2, const float* __restrict__ rb2,
    float* out, int osz, int offIest)
{
  int patch = blockIdx.x >> 6;
  int tid = threadIdx.x;
  const float* w0 = rw0 + patch*1024;
  const float* w1 = rw1 + patch*1024;
  const float* b0 = rb0 + patch*32;
  const float* b1 = rb1 + patch*32;
  const float* w2 = rw2 + patch*32;
  float b2s = rb2[patch];

  int p = (blockIdx.x & 63) * 256 + tid;
  int i = p >> 7, j = p & 127;
  int i1 = min(i+1, 127), j1 = min(j+1, 127);
  const float* base = pdata + (size_t)patch * 128*128*32;
  const float4* d00 = (const float4*)(base + (i*128 + j )*32);
  const float4* d01 = (const float4*)(base + (i*128 + j1)*32);
  const float4* d10 = (const float4*)(base + (i1*128 + j )*32);
  const float4* d11 = (const float4*)(base + (i1*128 + j1)*32);

  float f[32];
  #pragma unroll
  for (int q = 0; q < 8; q++){
    float4 a = d00[q], b = d01[q], cc = d10[q], d = d11[q];
    f[4*q+0] = 0.25f*(a.x+b.x+cc.x+d.x);
    f[4*q+1] = 0.25f*(a.y+b.y+cc.y+d.y);
    f[4*q+2] = 0.25f*(a.z+b.z+cc.z+d.z);
    f[4*q+3] = 0.25f*(a.w+b.w+cc.w+d.w);
  }

  float h[32];
  #pragma unroll
  for (int q = 0; q < 32; q++) h[q] = b0[q];
  for (int k = 0; k < 32; k++){
    float v = f[k];
    const float* row = w0 + k*32;
    #pragma unroll
    for (int q = 0; q < 32; q++) h[q] += v*row[q];
  }
  #pragma unroll
  for (int q = 0; q < 32; q++) h[q] = fmaxf(h[q], 0.f);

  float g[32];
  #pragma unroll
  for (int q = 0; q < 32; q++) g[q] = b1[q];
  for (int k = 0; k < 32; k++){
    float v = h[k];
    const float* row = w1 + k*32;
    #pragma unroll
    for (int q = 0; q < 32; q++) g[q] += v*row[q];
  }
  float o = b2s;
  #pragma unroll
  for (int k = 0; k < 32; k++) o += fmaxf(g[k], 0.f)*w2[k];

  int pr = (patch >> 1)*128 + i;
  int pc = (patch & 1)*128 + j;
  g_I[pr*256 + pc] = o;
  OUT_W(offIest + pr*256 + pc, o);
}

// ---------------- norm = 65536*sum(x^2), two-stage ----------------
__global__ __launch_bounds__(256) void k_norm1(const float* x){
  int tid = threadIdx.x;
  float4 v = ((const float4*)x)[(size_t)blockIdx.x*256 + tid];
  float s = v.x*v.x + v.y*v.y + v.z*v.z + v.w*v.w;
  __shared__ float red[256];
  red[tid] = s; __syncthreads();
  for (int w = 128; w > 0; w >>= 1){ if (tid < w) red[tid] += red[tid+w]; __syncthreads(); }
  if (tid == 0) g_partial[blockIdx.x] = red[0];
}

__global__ __launch_bounds__(256) void k_norm2(){
  int tid = threadIdx.x;
  int b = tid >> 4, l = tid & 15;
  float s = 0.f;
  #pragma unroll
  for (int j = 0; j < 4; j++) s += g_partial[b*64 + l + 16*j];
  #pragma unroll
  for (int d = 8; d > 0; d >>= 1) s += __shfl_down(s, d, 16);
  if (l == 0) g_norms[b] = 65536.0f * s;
}

// ---------------- field FFT (256): rows ----------------
__global__ __launch_bounds__(128) void k_fft_field_row(const float* x){
  int b = blockIdx.x >> 8, r = blockIdx.x & 255;
  __shared__ float re[256], im[256];
  int tid = threadIdx.x;
  for (int e = tid; e < 256; e += 128){
    float xv = x[((size_t)b*256 + r)*256 + e];
    float2 cs = g_cs[r*256 + e];
    re[e] = xv*cs.x; im[e] = xv*cs.y;
  }
  fft_dif_sc<256,false>(re, im, tid, 128);
  for (int e = tid; e < 256; e += 128)
    g_F[((size_t)b*256 + r)*256 + rev8(e)] = make_float2(re[e], im[e]);
}

// ---------------- field FFT: cols, radix-4, 8 per block, in place ----------------
__global__ __launch_bounds__(256) void k_fft_field_col(){
  __shared__ float2 buf[256*9];
  int b = blockIdx.x >> 5, v0 = (blockIdx.x & 31) << 3;
  int tid = threadIdx.x, c = tid & 7, rr = tid >> 3;
  const float2* Fr = &g_F[(size_t)b*256*256 + v0 + c];
  for (int r = rr; r < 256; r += 32) buf[r*9+c] = Fr[(size_t)r*256];
  #pragma unroll
  for (int q = 64; q >= 1; q >>= 2){
    __syncthreads();
    for (int g = rr; g < 64; g += 32){
      int k = g & (q-1);
      int base = ((g - k) << 2) + k;
      float2 x0 = buf[base*9+c], x1 = buf[(base+q)*9+c];
      float2 x2 = buf[(base+2*q)*9+c], x3 = buf[(base+3*q)*9+c];
      float2 t0=cadd(x0,x2), t1=csub(x0,x2), t2=cadd(x1,x3), t3=csub(x1,x3);
      float2 y0=cadd(t0,t2), y1=subi(t1,t3), y2=csub(t0,t2), y3=addi(t1,t3);
      if (q > 1){
        float2 w1 = g_tw[2*q+k], w2 = g_tw[q+k];
        float2 w3 = cmul(w1,w2);
        y1 = cmul(y1,w1); y2 = cmul(y2,w2); y3 = cmul(y3,w3);
      }
      buf[base*9+c]=y0; buf[(base+q)*9+c]=y1; buf[(base+2*q)*9+c]=y2; buf[(base+3*q)*9+c]=y3;
    }
  }
  __syncthreads();
  float2* Fw = &g_F[(size_t)b*256*256 + v0 + c];
  for (int p = rr; p < 256; p += 32)
    Fw[(size_t)rev4d8(p)*256] = buf[p*9+c];   // digit-reversed store -> natural bin order
}

// ------- fused: kernel magnitude (shift+flip+normalize) -> d_out, then padded row FFT -> KA -------
__global__ __launch_bounds__(256) void k_mag_krow(float* out, int osz, int offKer){
  int b = blockIdx.x >> 8, r = blockIdx.x & 255;
  __shared__ float re[512], im[512];
  int tid = threadIdx.x;
  float invn = 1.0f / g_norms[b];
  int a = (127 - r) & 255;
  for (int e = tid; e < 512; e += 256){
    float kv = 0.f;
    if (e < 256){
      int bb = (127 - e) & 255;
      float2 f = g_F[((size_t)b*256 + a)*256 + bb];
      kv = (f.x*f.x + f.y*f.y) * invn;
      OUT_W(offKer + b*65536 + r*256 + e, kv);
    }
    re[e] = kv; im[e] = 0.f;
  }
  fft_dif_sc<512,false>(re, im, tid, 256);
  for (int e = tid; e < 512; e += 256)
    g_KA[((size_t)b*256 + r)*512 + rev9(e)] = make_float2(re[e], im[e]);
}

// ---------------- Sf row pass = FFT(pad512(I_est rows)) ----------------
__global__ __launch_bounds__(256) void k_fft_S_row(){
  int r = blockIdx.x;
  __shared__ float re[512], im[512];
  int tid = threadIdx.x;
  for (int e = tid; e < 512; e += 256){
    re[e] = (e < 256) ? g_I[r*256 + e] : 0.f;
    im[e] = 0.f;
  }
  fft_dif_sc<512,false>(re, im, tid, 256);
  for (int e = tid; e < 512; e += 256) g_SfA[r*512 + rev9(e)] = make_float2(re[e], im[e]);
}

// ---- Sf col pass: SAME forward pipeline as col_mul_inv -> g_Sf stored in pi order ----
__global__ __launch_bounds__(256) void k_fft_S_col(){
  __shared__ float2 buf[512*9];
  int v0 = blockIdx.x << 3;
  int tid = threadIdx.x, c = tid & 7, rr = tid >> 3;
  int v = v0 + c;
  fold512_load(&g_SfA[v], buf, c, rr);
  dif4_stages_512(buf, c, rr);
  __syncthreads();
  for (int g = rr; g < 256; g += 32){
    int i0 = 2*g;
    float2 a = buf[i0*9+c], b = buf[(i0+1)*9+c];
    g_Sf[(size_t)i0*512 + v]     = cadd(a,b);
    g_Sf[(size_t)(i0+1)*512 + v] = csub(a,b);
  }
}

// ------- fused col pass: Kf col FFT (fold+r4) -> r2+mul+r2 -> inverse r4 -> partial last stage -------
__global__ __launch_bounds__(256) void k_col_mul_inv(){
  __shared__ float2 buf[512*9];
  int bi = blockIdx.x >> 6, v0 = (blockIdx.x & 63) << 3;
  int tid = threadIdx.x, c = tid & 7, rr = tid >> 3;
  int v = v0 + c;

  fold512_load(&g_KA[((size_t)bi*256)*512 + v], buf, c, rr);
  dif4_stages_512(buf, c, rr);

  __syncthreads();
  for (int g = rr; g < 256; g += 32){
    int i0 = 2*g;
    float2 a = buf[i0*9+c], b = buf[(i0+1)*9+c];
    float2 y0 = cadd(a,b), y1 = csub(a,b);
    float2 s0 = g_Sf[(size_t)i0*512 + v];
    float2 s1 = g_Sf[(size_t)(i0+1)*512 + v];
    float2 z0 = cmul(y0,s0), z1 = cmul(y1,s1);
    buf[i0*9+c]     = cadd(z0,z1);
    buf[(i0+1)*9+c] = csub(z0,z1);
  }

  #pragma unroll
  for (int q = 2; q <= 32; q <<= 2){
    __syncthreads();
    for (int g = rr; g < 128; g += 32){
      int k = g & (q-1);
      int base = ((g - k) << 2) + k;
      float2 z0 = buf[base*9+c], z1 = buf[(base+q)*9+c];
      float2 z2 = buf[(base+2*q)*9+c], z3 = buf[(base+3*q)*9+c];
      float2 w1 = g_tw[2*q+k], w2 = g_tw[q+k];
      float2 w3 = cmul(w1,w2);
      z1 = cmulj(z1,w1); z2 = cmulj(z2,w2); z3 = cmulj(z3,w3);
      float2 u0=cadd(z0,z2), u1=csub(z0,z2), u2=cadd(z1,z3), u3=csub(z1,z3);
      buf[base*9+c]       = cadd(u0,u2);
      buf[(base+q)*9+c]   = addi(u1,u3);
      buf[(base+2*q)*9+c] = csub(u0,u2);
      buf[(base+3*q)*9+c] = subi(u1,u3);
    }
  }

  __syncthreads();
  for (int i = rr; i < 128; i += 32){
    float2 z0 = buf[i*9+c], z1 = buf[(i+128)*9+c];
    float2 z2 = buf[(i+256)*9+c], z3 = buf[(i+384)*9+c];
    float2 w1 = g_tw[256+i], w2 = g_tw[128+i];
    float2 w3 = cmul(w1,w2);
    z1 = cmulj(z1,w1); z2 = cmulj(z2,w2); z3 = cmulj(z3,w3);
    float2 u0=cadd(z0,z2), u1=csub(z0,z2), u2=cadd(z1,z3), u3=csub(z1,z3);
    g_P[((size_t)bi*256 + i)*512 + v]       = addi(u1,u3); // conv row i+128
    g_P[((size_t)bi*256 + i + 128)*512 + v] = csub(u0,u2); // conv row i+256
  }
}

// ---------------- inverse row FFT + crop + scale + real ----------------
__global__ __launch_bounds__(256) void k_ifft_row(float* out, int osz){
  int b = blockIdx.x >> 8, ri = blockIdx.x & 255;
  __shared__ float re[512], im[512];
  int tid = threadIdx.x;
  for (int e = tid; e < 512; e += 256){
    float2 p = g_P[((size_t)b*256 + ri)*512 + e];
    re[e] = p.x; im[e] = p.y;
  }
  fft_dif_sc<512,true>(re, im, tid, 256);      // inverse, natural in -> bit-rev out
  const float sc = 1.0f / 262144.0f;           // 1/(512*512)
  for (int e = tid; e < 512; e += 256){
    int vo = rev9(e);
    if (vo >= 128 && vo < 384)
      OUT_W(b*65536 + ri*256 + (vo - 128), re[e] * sc);
  }
}

extern "C" void kernel_launch(void* const* d_in, const int* in_sizes, int n_in,
                              void* d_out, int out_size, void* d_ws, size_t ws_size,
                              hipStream_t stream) {
  static const int expect[21] = {
    16*65536, 16, 4*128*128*32,
    4*32*32, 4*32, 4*32*32, 4*32, 4*32, 4,
    60*32, 32, 32*32, 32, 32, 32, 32*32, 32, 32, 32, 32, 1
  };
  if (n_in < 21) return;
  for (int i = 0; i < 21; i++) if (in_sizes[i] != expect[i]) return;

  const float* x_batch = (const float*)d_in[0];
  const float* pdata = (const float*)d_in[2];
  const float* rw0 = (const float*)d_in[3];
  const float* rb0 = (const float*)d_in[4];
  const float* rw1 = (const float*)d_in[5];
  const float* rb1 = (const float*)d_in[6];
  const float* rw2 = (const float*)d_in[7];
  const float* rb2 = (const float*)d_in[8];
  const float* gw0 = (const float*)d_in[9];
  const float* gb0 = (const float*)d_in[10];
  const float* gw1 = (const float*)d_in[11];
  const float* gb1 = (const float*)d_in[12];
  const float* l1w = (const float*)d_in[13];
  const float* l1b = (const float*)d_in[14];
  const float* gw2 = (const float*)d_in[15];
  const float* gb2 = (const float*)d_in[16];
  const float* l2w = (const float*)d_in[17];
  const float* l2b = (const float*)d_in[18];
  const float* gw3 = (const float*)d_in[19];
  const float* gb3 = (const float*)d_in[20];

  float* out = (float*)d_out;

  int interleaved = (out_size >= 5308416) ? 1 : 0;
  int offKer  = 1048576;
  int offG    = 2097152;
  int offPhs  = interleaved ? 4194304 : 3145728;
  int offIest = interleaved ? 5242880 : 4194304;

  k_twiddle<<<2, 256, 0, stream>>>();
  k_gmlp<<<256, 256, 0, stream>>>(gw0, gb0, gw1, gb1, l1w, l1b, gw2, gb2,
                                  l2w, l2b, gw3, gb3, out, out_size, offG, offPhs, interleaved);
  k_patch<<<256, 256, 0, stream>>>(pdata, rw0, rb0, rw1, rb1, rw2, rb2, out, out_size, offIest);
  k_norm1<<<1024, 256, 0, stream>>>(x_batch);
  k_norm2<<<1, 256, 0, stream>>>();
  k_fft_S_row<<<256, 256, 0, stream>>>();
  k_fft_S_col<<<64, 256, 0, stream>>>();
  k_fft_field_row<<<4096, 128, 0, stream>>>(x_batch);
  k_fft_field_col<<<512, 256, 0, stream>>>();
  k_mag_krow<<<4096, 256, 0, stream>>>(out, out_size, offKer);
  k_col_mul_inv<<<1024, 256, 0, stream>>>();
  k_ifft_row<<<4096, 256, 0, stream>>>(out, out_size);
}